// Round 9
// baseline (1229.863 us; speedup 1.0000x reference)
//
#include <hip/hip_runtime.h>

#define COL_DIM 4096
#define ROW_DIM 1024
#define NUM_LAYERS 3
#define KNN_E 16384
#define GENET_E 131072
#define TBK 32

typedef __attribute__((ext_vector_type(8))) short short8;
typedef __attribute__((ext_vector_type(4))) float f32x4;

// ---------------- fp32 -> bf16 hi/lo helpers ----------------
__device__ inline unsigned short f2bf(float f) {
  unsigned int u = __float_as_uint(f);
  u += 0x7FFFu + ((u >> 16) & 1u); // RNE
  return (unsigned short)(u >> 16);
}
__device__ inline float bf2f(unsigned short h) {
  return __uint_as_float(((unsigned int)h) << 16);
}

// ---------------- transpose + split: in[R][C] -> outf/outh/outl [C][R] --------
__global__ void transpose_split_kernel(const float* __restrict__ in,
                                       float* __restrict__ outf,
                                       unsigned short* __restrict__ outh,
                                       unsigned short* __restrict__ outl,
                                       int R, int C) {
  __shared__ float tile[32][33];
  int c0 = blockIdx.x * 32, r0 = blockIdx.y * 32;
  int tx = threadIdx.x, ty = threadIdx.y; // 32 x 8
#pragma unroll
  for (int i = 0; i < 32; i += 8)
    tile[ty + i][tx] = in[(size_t)(r0 + ty + i) * C + c0 + tx];
  __syncthreads();
#pragma unroll
  for (int i = 0; i < 32; i += 8) {
    float v = tile[tx][ty + i];
    size_t o = (size_t)(c0 + ty + i) * R + r0 + tx;
    outf[o] = v;
    unsigned short h = f2bf(v);
    outh[o] = h;
    outl[o] = f2bf(v - bf2f(h));
  }
}

// ---------------- CSR build ----------------
__global__ void count_kernel(const int* __restrict__ dst, int E, int* __restrict__ cnt) {
  int e = blockIdx.x * 256 + threadIdx.x;
  if (e < E) atomicAdd(&cnt[dst[e]], 1);
}

__global__ void scan_kernel(const int* __restrict__ cnt, int* __restrict__ indptr, int n) {
  __shared__ int s[1024];
  __shared__ int base_s;
  int tid = threadIdx.x;
  if (tid == 0) { base_s = 0; indptr[0] = 0; }
  __syncthreads();
  for (int c = 0; c < n; c += 1024) {
    int i = c + tid;
    int v = (i < n) ? cnt[i] : 0;
    s[tid] = v;
    __syncthreads();
    for (int off = 1; off < 1024; off <<= 1) {
      int t = (tid >= off) ? s[tid - off] : 0;
      __syncthreads();
      s[tid] += t;
      __syncthreads();
    }
    if (i < n) indptr[i + 1] = base_s + s[tid];
    __syncthreads();
    if (tid == 0) base_s += s[1023];
    __syncthreads();
  }
}

__global__ void copy_int_kernel(const int* __restrict__ a, int* __restrict__ b, int n) {
  int i = blockIdx.x * 256 + threadIdx.x;
  if (i < n) b[i] = a[i];
}

__global__ void fill_kernel(const int* __restrict__ src, const int* __restrict__ dst, int E,
                            int* __restrict__ cursor, int* __restrict__ idx) {
  int e = blockIdx.x * 256 + threadIdx.x;
  if (e < E) {
    int p = atomicAdd(&cursor[dst[e]], 1);
    idx[p] = src[e];
  }
}

// ---------------- wave-per-bucket rank sort (deterministic: sorted by value) ---
__global__ void rank_sort_kernel(const int* __restrict__ indptr, int* __restrict__ idx,
                                 int n) {
  int wv = threadIdx.x >> 6, lane = threadIdx.x & 63;
  int b = blockIdx.x * (blockDim.x >> 6) + wv;
  if (b >= n) return;
  int lo = indptr[b];
  int d = indptr[b + 1] - lo;
  if (d <= 1) return;
  if (d <= 256) {
    int v0 = (lane < d) ? idx[lo + lane] : 0x7fffffff;
    int v1 = (64 + lane < d) ? idx[lo + 64 + lane] : 0x7fffffff;
    int v2 = (128 + lane < d) ? idx[lo + 128 + lane] : 0x7fffffff;
    int v3 = (192 + lane < d) ? idx[lo + 192 + lane] : 0x7fffffff;
    int r0 = 0, r1 = 0, r2 = 0, r3 = 0;
    for (int j = 0; j < d; j++) {
      int q = j >> 6;
      int sel = (q == 0) ? v0 : (q == 1) ? v1 : (q == 2) ? v2 : v3;
      int bj = __shfl(sel, j & 63);
      r0 += (bj < v0 || (bj == v0 && j < lane)) ? 1 : 0;
      r1 += (bj < v1 || (bj == v1 && j < 64 + lane)) ? 1 : 0;
      r2 += (bj < v2 || (bj == v2 && j < 128 + lane)) ? 1 : 0;
      r3 += (bj < v3 || (bj == v3 && j < 192 + lane)) ? 1 : 0;
    }
    if (lane < d) idx[lo + r0] = v0;
    if (64 + lane < d) idx[lo + r1] = v1;
    if (128 + lane < d) idx[lo + r2] = v2;
    if (192 + lane < d) idx[lo + r3] = v3;
  } else if (lane == 0) {
    for (int i = lo + 1; i < lo + d; i++) {
      int v = idx[i];
      int j = i - 1;
      while (j >= lo && idx[j] > v) { idx[j + 1] = idx[j]; j--; }
      idx[j + 1] = v;
    }
  }
}

// ---------------- neighbor mean, XCD-sliced, + split to bf16 hi/lo ------------
__global__ void agg_slice_kernel(const float* __restrict__ src,
                                 unsigned short* __restrict__ dh,
                                 unsigned short* __restrict__ dl,
                                 const int* __restrict__ indptr,
                                 const int* __restrict__ idx, int D, int tprsh) {
  int tid = threadIdx.x;
  int d = blockIdx.y * (256 >> tprsh) + (tid >> tprsh);
  int k4 = blockIdx.x * (1 << tprsh) + (tid & ((1 << tprsh) - 1));
  int lo = indptr[d], hi = indptr[d + 1];
  float4 s = make_float4(0.f, 0.f, 0.f, 0.f);
  for (int j = lo; j < hi; j++) {
    float4 v = ((const float4*)(src + (size_t)idx[j] * D))[k4];
    s.x += v.x; s.y += v.y; s.z += v.z; s.w += v.w;
  }
  int c = hi - lo;
  float inv = 1.f / (float)(c > 0 ? c : 1);
  s.x *= inv; s.y *= inv; s.z *= inv; s.w *= inv;
  ushort4 h, l;
  h.x = f2bf(s.x); l.x = f2bf(s.x - bf2f(h.x));
  h.y = f2bf(s.y); l.y = f2bf(s.y - bf2f(h.y));
  h.z = f2bf(s.z); l.z = f2bf(s.z - bf2f(h.z));
  h.w = f2bf(s.w); l.w = f2bf(s.w - bf2f(h.w));
  ((ushort4*)(dh + (size_t)d * D))[k4] = h;
  ((ushort4*)(dl + (size_t)d * D))[k4] = l;
}

// ---------------- plain split for weights ----------------
__global__ void split_kernel(const float* __restrict__ src, unsigned short* __restrict__ dh,
                             unsigned short* __restrict__ dl, int n4) {
  int i = blockIdx.x * 256 + threadIdx.x;
  int stride = gridDim.x * 256;
  for (; i < n4; i += stride) {
    float4 v = ((const float4*)src)[i];
    ushort4 h, l;
    h.x = f2bf(v.x); l.x = f2bf(v.x - bf2f(h.x));
    h.y = f2bf(v.y); l.y = f2bf(v.y - bf2f(h.y));
    h.z = f2bf(v.z); l.z = f2bf(v.z - bf2f(h.z));
    h.w = f2bf(v.w); l.w = f2bf(v.w - bf2f(h.w));
    ((ushort4*)dh)[i] = h;
    ((ushort4*)dl)[i] = l;
  }
}

// ---------------- virtual-K pipelined bf16 NT GEMM ----------------
// C_partial[sk][4096][1024] = sum over virtual K-tiles of A_seg[m][k]*B_seg[n][k].
// 6 segments of length KA each (2 products x 3 split-bf16 sweeps).
// 256x256 tile, BK=32, 8 waves (512 thr), wave tile 128x64 (8x4 frags).
// 4-buffer LDS ring (128KB), 3-tile prefetch depth, 1 barrier + vmcnt(8)/tile.
// Hazard invariants:
//  - tile t's 4 loads landed before its reads: vmcnt(8) at end of t-1 (12
//    outstanding max, FIFO) + barrier (all waves' loads).
//  - buf (t+3)&3 == (t-1)&3 rewritten only after end-of-(t-1) barrier.
#define GLDS(g, l)                                                             \
  __builtin_amdgcn_global_load_lds(                                            \
      (const __attribute__((address_space(1))) void*)(g),                      \
      (__attribute__((address_space(3))) void*)(l), 16, 0, 0)

#define SEGA(si) ((si)==0?A0s:(si)==1?A1s:(si)==2?A2s:(si)==3?A3s:(si)==4?A4s:A5s)
#define SEGB(si) ((si)==0?B0s:(si)==1?B1s:(si)==2?B2s:(si)==3?B3s:(si)==4?B4s:B5s)

#define STAGE_A(vt, buf)                                                       \
  {                                                                            \
    int si_ = (vt) >> segshift;                                                \
    size_t ko_ = (size_t)((vt) & segmask) * TBK;                               \
    const unsigned short* As_ = SEGA(si_);                                     \
    GLDS(As_ + gA0 + ko_, &sm[buf][0][uA0 * 8]);                               \
    GLDS(As_ + gA1 + ko_, &sm[buf][0][uA1 * 8]);                               \
  }
#define STAGE_B(vt, buf)                                                       \
  {                                                                            \
    int si_ = (vt) >> segshift;                                                \
    size_t ko_ = (size_t)((vt) & segmask) * TBK;                               \
    const unsigned short* Bs_ = SEGB(si_);                                     \
    GLDS(Bs_ + gB0 + ko_, &sm[buf][1][uA0 * 8]);                               \
    GLDS(Bs_ + gB1 + ko_, &sm[buf][1][uA1 * 8]);                               \
  }

__global__ __launch_bounds__(512, 2) void vk_gemm_kernel(
    const unsigned short* __restrict__ A0s, const unsigned short* __restrict__ A1s,
    const unsigned short* __restrict__ A2s, const unsigned short* __restrict__ A3s,
    const unsigned short* __restrict__ A4s, const unsigned short* __restrict__ A5s,
    const unsigned short* __restrict__ B0s, const unsigned short* __restrict__ B1s,
    const unsigned short* __restrict__ B2s, const unsigned short* __restrict__ B3s,
    const unsigned short* __restrict__ B4s, const unsigned short* __restrict__ B5s,
    float* __restrict__ P0, float* __restrict__ P1,
    float* __restrict__ P2, float* __restrict__ P3,
    int KA, int segshift, int tpb) {
  __shared__ unsigned short sm[4][2][8192]; // 4 bufs x {A,B} x 256rows*32k = 128KB
  const int tid = threadIdx.x;
  const int lane = tid & 63;
  const int wid = tid >> 6;            // 8 waves
  const int wm = wid >> 2, wn = wid & 3; // wave tile: rows wm*128.., cols wn*64..

  const int bid = blockIdx.x;                 // 256 blocks
  const int swz = (bid & 7) * 32 + (bid >> 3); // XCD-chunked
  const int sk = swz >> 6;                    // splitK 0..3
  const int tile = swz & 63;                  // 16 m-tiles x 4 n-tiles
  const int bm0 = (tile >> 2) * 256;
  const int bn0 = (tile & 3) * 256;
  const int vt0 = sk * tpb;
  const int segmask = (1 << segshift) - 1;

  // staging: per operand 1024 units of 16B; thread handles units tid, tid+512.
  // physical slot q holds logical k-slot q^(r&3) (conflict-free involution).
  const int uA0 = tid, uA1 = tid + 512;
  const int r0 = uA0 >> 2, r1 = uA1 >> 2;
  const int q0 = (uA0 & 3) ^ (r0 & 3), q1 = (uA1 & 3) ^ (r1 & 3);
  const size_t gA0 = (size_t)(bm0 + r0) * KA + q0 * 8;
  const size_t gA1 = (size_t)(bm0 + r1) * KA + q1 * 8;
  const size_t gB0 = (size_t)(bn0 + r0) * KA + q0 * 8;
  const size_t gB1 = (size_t)(bn0 + r1) * KA + q1 * 8;

  // ds_read: frag row r -> r&3 == lane&3; physical slot = (lane>>4)^(lane&3).
  const int xslot = ((lane >> 4) ^ (lane & 3)) * 8;
  const int offA = (wm * 128 + (lane & 15)) * 32 + xslot; // +i*512 per frag
  const int offB = (wn * 64 + (lane & 15)) * 32 + xslot;  // +j*512 per frag

  f32x4 acc[8][4];
#pragma unroll
  for (int i = 0; i < 8; i++)
#pragma unroll
    for (int j = 0; j < 4; j++) acc[i][j] = (f32x4)(0.f);

  // prologue: stage tiles vt0..vt0+2 into bufs 0..2 (tpb >= 48 always)
  STAGE_A(vt0 + 0, 0); STAGE_B(vt0 + 0, 0);
  STAGE_A(vt0 + 1, 1); STAGE_B(vt0 + 1, 1);
  STAGE_A(vt0 + 2, 2); STAGE_B(vt0 + 2, 2);
  asm volatile("s_waitcnt vmcnt(8)" ::: "memory"); // tile 0 landed (own loads)
  asm volatile("" ::: "memory");
  __builtin_amdgcn_s_barrier();                    // everyone's tile-0 loads landed
  asm volatile("" ::: "memory");

#pragma unroll 1
  for (int t = 0; t < tpb; ++t) {
    const int buf = t & 3;
    const unsigned short* smA = &sm[buf][0][0];
    const unsigned short* smB = &sm[buf][1][0];
    short8 av[4], bv[4], aw[4];
    // phase 0: frags i=0..3
#pragma unroll
    for (int i = 0; i < 4; i++) av[i] = *(const short8*)(smA + offA + i * 512);
#pragma unroll
    for (int j = 0; j < 4; j++) bv[j] = *(const short8*)(smB + offB + j * 512);
    if (t + 3 < tpb) STAGE_A(vt0 + t + 3, (t + 3) & 3);
    __builtin_amdgcn_s_setprio(1);
#pragma unroll
    for (int i = 0; i < 4; i++)
#pragma unroll
      for (int j = 0; j < 4; j++)
        acc[i][j] = __builtin_amdgcn_mfma_f32_16x16x32_bf16(av[i], bv[j], acc[i][j], 0, 0, 0);
    __builtin_amdgcn_s_setprio(0);
    // phase 1: frags i=4..7
#pragma unroll
    for (int i = 0; i < 4; i++) aw[i] = *(const short8*)(smA + offA + (i + 4) * 512);
    if (t + 3 < tpb) STAGE_B(vt0 + t + 3, (t + 3) & 3);
    __builtin_amdgcn_s_setprio(1);
#pragma unroll
    for (int i = 0; i < 4; i++)
#pragma unroll
      for (int j = 0; j < 4; j++)
        acc[i + 4][j] = __builtin_amdgcn_mfma_f32_16x16x32_bf16(aw[i], bv[j], acc[i + 4][j], 0, 0, 0);
    __builtin_amdgcn_s_setprio(0);
    // tile boundary: ensure tile t+1 landed, all waves past reads of buf
    if (t + 1 < tpb) {
      if (t + 3 < tpb) {
        asm volatile("s_waitcnt vmcnt(8)" ::: "memory");
      } else if (t + 2 < tpb) {
        asm volatile("s_waitcnt vmcnt(4)" ::: "memory");
      } else {
        asm volatile("s_waitcnt vmcnt(0)" ::: "memory");
      }
      asm volatile("" ::: "memory");
      __builtin_amdgcn_s_barrier();
      asm volatile("" ::: "memory");
    }
  }

  float* P = sk == 0 ? P0 : sk == 1 ? P1 : sk == 2 ? P2 : P3;
  const int rq = (lane >> 4) * 4;
  const int cq = lane & 15;
#pragma unroll
  for (int i = 0; i < 8; i++) {
#pragma unroll
    for (int j = 0; j < 4; j++) {
#pragma unroll
      for (int e = 0; e < 4; e++) {
        int row = bm0 + wm * 128 + i * 16 + rq + e;
        int col = bn0 + wn * 64 + j * 16 + cq;
        P[(size_t)row * 1024 + col] = acc[i][j][e];
      }
    }
  }
}

// ---------------- combine4: C = leaky(P0..P3 + bias[row]) + hi/lo split --------
__global__ void combine_split_kernel(const float* __restrict__ P0, const float* __restrict__ P1,
                                     const float* __restrict__ P2, const float* __restrict__ P3,
                                     const float* __restrict__ bias, float* __restrict__ Cf,
                                     unsigned short* __restrict__ Ch,
                                     unsigned short* __restrict__ Cl) {
  int i = blockIdx.x * 256 + threadIdx.x; // float4 index, 1M total
  float4 a = ((const float4*)P0)[i];
  float4 b = ((const float4*)P1)[i];
  float4 c = ((const float4*)P2)[i];
  float4 d = ((const float4*)P3)[i];
  float bb = bias[(i * 4) >> 10];
  float4 v;
  v.x = a.x + b.x + c.x + d.x + bb;
  v.y = a.y + b.y + c.y + d.y + bb;
  v.z = a.z + b.z + c.z + d.z + bb;
  v.w = a.w + b.w + c.w + d.w + bb;
  v.x = v.x > 0.f ? v.x : 0.01f * v.x;
  v.y = v.y > 0.f ? v.y : 0.01f * v.y;
  v.z = v.z > 0.f ? v.z : 0.01f * v.z;
  v.w = v.w > 0.f ? v.w : 0.01f * v.w;
  ((float4*)Cf)[i] = v;
  ushort4 h, l;
  h.x = f2bf(v.x); l.x = f2bf(v.x - bf2f(h.x));
  h.y = f2bf(v.y); l.y = f2bf(v.y - bf2f(h.y));
  h.z = f2bf(v.z); l.z = f2bf(v.z - bf2f(h.z));
  h.w = f2bf(v.w); l.w = f2bf(v.w - bf2f(h.w));
  ((ushort4*)Ch)[i] = h;
  ((ushort4*)Cl)[i] = l;
}

// ---------------- combine4: C = leaky(P0..P3 + bias[col]) ----------------
__global__ void combine_kernel(const float* __restrict__ P0, const float* __restrict__ P1,
                               const float* __restrict__ P2, const float* __restrict__ P3,
                               const float* __restrict__ bias, float* __restrict__ C) {
  int i = blockIdx.x * 256 + threadIdx.x;
  float4 a = ((const float4*)P0)[i];
  float4 b = ((const float4*)P1)[i];
  float4 c = ((const float4*)P2)[i];
  float4 d = ((const float4*)P3)[i];
  float4 bb = *(const float4*)(bias + ((i * 4) & 1023));
  float4 v;
  v.x = a.x + b.x + c.x + d.x + bb.x;
  v.y = a.y + b.y + c.y + d.y + bb.y;
  v.z = a.z + b.z + c.z + d.z + bb.z;
  v.w = a.w + b.w + c.w + d.w + bb.w;
  v.x = v.x > 0.f ? v.x : 0.01f * v.x;
  v.y = v.y > 0.f ? v.y : 0.01f * v.y;
  v.z = v.z > 0.f ? v.z : 0.01f * v.z;
  v.w = v.w > 0.f ? v.w : 0.01f * v.w;
  ((float4*)C)[i] = v;
}

extern "C" void kernel_launch(void* const* d_in, const int* in_sizes, int n_in,
                              void* d_out, int out_size, void* d_ws, size_t ws_size,
                              hipStream_t stream) {
  const float* x      = (const float*)d_in[0];
  const float* col_Wl = (const float*)d_in[1];
  const float* col_Wr = (const float*)d_in[2];
  const float* col_b  = (const float*)d_in[3];
  const float* row_Wl = (const float*)d_in[4];
  const float* row_Wr = (const float*)d_in[5];
  const float* row_b  = (const float*)d_in[6];
  const int*   knn    = (const int*)d_in[7];   // [2][KNN_E]
  const int*   genet  = (const int*)d_in[8];   // [2][GENET_E]
  float* out = (float*)d_out;

  const size_t MAT = (size_t)COL_DIM * ROW_DIM; // 4M elements
  const size_t WCOL = (size_t)COL_DIM * COL_DIM; // 16M
  const size_t WROW = (size_t)ROW_DIM * ROW_DIM; // 1M
  char* w = (char*)d_ws;
  // lifetimes: X1f = ET(fp32, agg src) then E1(fp32); X2 = ETh/l then E1h/l;
  // X3 = Mh/l then Gh/l. W splits live only across their branch's GEMM.
  float* X1f = (float*)w; w += MAT * 4;                 // 16MB
  unsigned short* X2h = (unsigned short*)w; w += MAT * 2;
  unsigned short* X2l = (unsigned short*)w; w += MAT * 2;
  unsigned short* X3h = (unsigned short*)w; w += MAT * 2;
  unsigned short* X3l = (unsigned short*)w; w += MAT * 2;
  unsigned short* WLh = (unsigned short*)w; w += WCOL * 2; // 32MB
  unsigned short* WLl = (unsigned short*)w; w += WCOL * 2;
  unsigned short* WRh = (unsigned short*)w; w += WCOL * 2;
  unsigned short* WRl = (unsigned short*)w; w += WCOL * 2;
  unsigned short* RLh = (unsigned short*)w; w += WROW * 2; // 2MB
  unsigned short* RLl = (unsigned short*)w; w += WROW * 2;
  unsigned short* RRh = (unsigned short*)w; w += WROW * 2;
  unsigned short* RRl = (unsigned short*)w; w += WROW * 2;
  float* PP0 = (float*)w; w += MAT * 4;
  float* PP1 = (float*)w; w += MAT * 4;
  float* PP2 = (float*)w; w += MAT * 4;
  float* PP3 = (float*)w; w += MAT * 4;
  int* kcnt = (int*)w; w += 1024 * 4;
  int* kptr = (int*)w; w += 1025 * 4;
  int* kidx = (int*)w; w += KNN_E * 4;
  int* gcnt = (int*)w; w += 4096 * 4;
  int* gptr = (int*)w; w += 4097 * 4;
  int* gidx = (int*)w; w += (size_t)GENET_E * 4;

  // ---- CSR build (deterministic via per-bucket value sort) ----
  hipMemsetAsync(kcnt, 0, 1024 * 4, stream);
  hipMemsetAsync(gcnt, 0, 4096 * 4, stream);
  count_kernel<<<KNN_E / 256, 256, 0, stream>>>(knn + KNN_E, KNN_E, kcnt);
  count_kernel<<<GENET_E / 256, 256, 0, stream>>>(genet + GENET_E, GENET_E, gcnt);
  scan_kernel<<<1, 1024, 0, stream>>>(kcnt, kptr, 1024);
  scan_kernel<<<1, 1024, 0, stream>>>(gcnt, gptr, 4096);
  copy_int_kernel<<<4, 256, 0, stream>>>(kptr, kcnt, 1024);
  copy_int_kernel<<<16, 256, 0, stream>>>(gptr, gcnt, 4096);
  fill_kernel<<<KNN_E / 256, 256, 0, stream>>>(knn, knn + KNN_E, KNN_E, kcnt, kidx);
  fill_kernel<<<GENET_E / 256, 256, 0, stream>>>(genet, genet + GENET_E, GENET_E, gcnt, gidx);
  rank_sort_kernel<<<256, 256, 0, stream>>>(kptr, kidx, 1024);
  rank_sort_kernel<<<1024, 256, 0, stream>>>(gptr, gidx, 4096);

  const float* Ein = x;
  for (int i = 0; i < NUM_LAYERS; i++) {
    const float* cWl = col_Wl + (size_t)i * WCOL;
    const float* cWr = col_Wr + (size_t)i * WCOL;
    const float* cb  = col_b + (size_t)i * COL_DIM;
    const float* rWl = row_Wl + (size_t)i * WROW;
    const float* rWr = row_Wr + (size_t)i * WROW;
    const float* rb  = row_b + (size_t)i * ROW_DIM;

    // ---- column branch: E1 = leaky(cWl@M^T + cWr@ET^T + cb[row]) ----
    transpose_split_kernel<<<dim3(ROW_DIM / 32, COL_DIM / 32), dim3(32, 8), 0, stream>>>(
        Ein, X1f, X2h, X2l, COL_DIM, ROW_DIM);
    agg_slice_kernel<<<dim3(8, 512), 256, 0, stream>>>(X1f, X3h, X3l, kptr, kidx,
                                                       COL_DIM, 7);
    split_kernel<<<2048, 256, 0, stream>>>(cWl, WLh, WLl, (int)(WCOL / 4));
    split_kernel<<<2048, 256, 0, stream>>>(cWr, WRh, WRl, (int)(WCOL / 4));
    // segments: (WLh,Mh)(WLh,Ml)(WLl,Mh) (WRh,ETh)(WRh,ETl)(WRl,ETh)
    vk_gemm_kernel<<<256, 512, 0, stream>>>(
        WLh, WLh, WLl, WRh, WRh, WRl,
        X3h, X3l, X3h, X2h, X2l, X2h,
        PP0, PP1, PP2, PP3, COL_DIM, 7, 192);
    combine_split_kernel<<<4096, 256, 0, stream>>>(PP0, PP1, PP2, PP3, cb,
                                                   X1f, X2h, X2l); // E1 f32+h/l
    // ---- row branch: out = leaky(G@rWl^T + E1@rWr^T + rb[col]) ----
    agg_slice_kernel<<<dim3(8, 512), 256, 0, stream>>>(X1f, X3h, X3l, gptr, gidx,
                                                       ROW_DIM, 5);
    split_kernel<<<1024, 256, 0, stream>>>(rWl, RLh, RLl, (int)(WROW / 4));
    split_kernel<<<1024, 256, 0, stream>>>(rWr, RRh, RRl, (int)(WROW / 4));
    // segments: (Gh,RLh)(Gh,RLl)(Gl,RLh) (E1h,RRh)(E1h,RRl)(E1l,RRh)
    vk_gemm_kernel<<<256, 512, 0, stream>>>(
        X3h, X3h, X3l, X2h, X2h, X2l,
        RLh, RLl, RLh, RRh, RRl, RRh,
        PP0, PP1, PP2, PP3, ROW_DIM, 5, 48);
    combine_kernel<<<4096, 256, 0, stream>>>(PP0, PP1, PP2, PP3, rb, out);

    Ein = out;
  }
}

// Round 10
// 1218.486 us; speedup vs baseline: 1.0093x; 1.0093x over previous
//
#include <hip/hip_runtime.h>

#define COL_DIM 4096
#define ROW_DIM 1024
#define NUM_LAYERS 3
#define KNN_E 16384
#define GENET_E 131072
#define TBK 32

typedef __attribute__((ext_vector_type(8))) short short8;
typedef __attribute__((ext_vector_type(4))) float f32x4;

// ---------------- fp32 -> bf16 hi/lo helpers ----------------
__device__ inline unsigned short f2bf(float f) {
  unsigned int u = __float_as_uint(f);
  u += 0x7FFFu + ((u >> 16) & 1u); // RNE
  return (unsigned short)(u >> 16);
}
__device__ inline float bf2f(unsigned short h) {
  return __uint_as_float(((unsigned int)h) << 16);
}

// ---------------- transpose + split: in[R][C] -> outf/outh/outl [C][R] --------
__global__ void transpose_split_kernel(const float* __restrict__ in,
                                       float* __restrict__ outf,
                                       unsigned short* __restrict__ outh,
                                       unsigned short* __restrict__ outl,
                                       int R, int C) {
  __shared__ float tile[32][33];
  int c0 = blockIdx.x * 32, r0 = blockIdx.y * 32;
  int tx = threadIdx.x, ty = threadIdx.y; // 32 x 8
#pragma unroll
  for (int i = 0; i < 32; i += 8)
    tile[ty + i][tx] = in[(size_t)(r0 + ty + i) * C + c0 + tx];
  __syncthreads();
#pragma unroll
  for (int i = 0; i < 32; i += 8) {
    float v = tile[tx][ty + i];
    size_t o = (size_t)(c0 + ty + i) * R + r0 + tx;
    outf[o] = v;
    unsigned short h = f2bf(v);
    outh[o] = h;
    outl[o] = f2bf(v - bf2f(h));
  }
}

// ---------------- CSR build ----------------
__global__ void count_kernel(const int* __restrict__ dst, int E, int* __restrict__ cnt) {
  int e = blockIdx.x * 256 + threadIdx.x;
  if (e < E) atomicAdd(&cnt[dst[e]], 1);
}

__global__ void scan_kernel(const int* __restrict__ cnt, int* __restrict__ indptr, int n) {
  __shared__ int s[1024];
  __shared__ int base_s;
  int tid = threadIdx.x;
  if (tid == 0) { base_s = 0; indptr[0] = 0; }
  __syncthreads();
  for (int c = 0; c < n; c += 1024) {
    int i = c + tid;
    int v = (i < n) ? cnt[i] : 0;
    s[tid] = v;
    __syncthreads();
    for (int off = 1; off < 1024; off <<= 1) {
      int t = (tid >= off) ? s[tid - off] : 0;
      __syncthreads();
      s[tid] += t;
      __syncthreads();
    }
    if (i < n) indptr[i + 1] = base_s + s[tid];
    __syncthreads();
    if (tid == 0) base_s += s[1023];
    __syncthreads();
  }
}

__global__ void copy_int_kernel(const int* __restrict__ a, int* __restrict__ b, int n) {
  int i = blockIdx.x * 256 + threadIdx.x;
  if (i < n) b[i] = a[i];
}

__global__ void fill_kernel(const int* __restrict__ src, const int* __restrict__ dst, int E,
                            int* __restrict__ cursor, int* __restrict__ idx) {
  int e = blockIdx.x * 256 + threadIdx.x;
  if (e < E) {
    int p = atomicAdd(&cursor[dst[e]], 1);
    idx[p] = src[e];
  }
}

// ---------------- wave-per-bucket rank sort (deterministic: sorted by value) ---
__global__ void rank_sort_kernel(const int* __restrict__ indptr, int* __restrict__ idx,
                                 int n) {
  int wv = threadIdx.x >> 6, lane = threadIdx.x & 63;
  int b = blockIdx.x * (blockDim.x >> 6) + wv;
  if (b >= n) return;
  int lo = indptr[b];
  int d = indptr[b + 1] - lo;
  if (d <= 1) return;
  if (d <= 256) {
    int v0 = (lane < d) ? idx[lo + lane] : 0x7fffffff;
    int v1 = (64 + lane < d) ? idx[lo + 64 + lane] : 0x7fffffff;
    int v2 = (128 + lane < d) ? idx[lo + 128 + lane] : 0x7fffffff;
    int v3 = (192 + lane < d) ? idx[lo + 192 + lane] : 0x7fffffff;
    int r0 = 0, r1 = 0, r2 = 0, r3 = 0;
    for (int j = 0; j < d; j++) {
      int q = j >> 6;
      int sel = (q == 0) ? v0 : (q == 1) ? v1 : (q == 2) ? v2 : v3;
      int bj = __shfl(sel, j & 63);
      r0 += (bj < v0 || (bj == v0 && j < lane)) ? 1 : 0;
      r1 += (bj < v1 || (bj == v1 && j < 64 + lane)) ? 1 : 0;
      r2 += (bj < v2 || (bj == v2 && j < 128 + lane)) ? 1 : 0;
      r3 += (bj < v3 || (bj == v3 && j < 192 + lane)) ? 1 : 0;
    }
    if (lane < d) idx[lo + r0] = v0;
    if (64 + lane < d) idx[lo + r1] = v1;
    if (128 + lane < d) idx[lo + r2] = v2;
    if (192 + lane < d) idx[lo + r3] = v3;
  } else if (lane == 0) {
    for (int i = lo + 1; i < lo + d; i++) {
      int v = idx[i];
      int j = i - 1;
      while (j >= lo && idx[j] > v) { idx[j + 1] = idx[j]; j--; }
      idx[j + 1] = v;
    }
  }
}

// ---------------- neighbor mean, XCD-sliced, + split to bf16 hi/lo ------------
__global__ void agg_slice_kernel(const float* __restrict__ src,
                                 unsigned short* __restrict__ dh,
                                 unsigned short* __restrict__ dl,
                                 const int* __restrict__ indptr,
                                 const int* __restrict__ idx, int D, int tprsh) {
  int tid = threadIdx.x;
  int d = blockIdx.y * (256 >> tprsh) + (tid >> tprsh);
  int k4 = blockIdx.x * (1 << tprsh) + (tid & ((1 << tprsh) - 1));
  int lo = indptr[d], hi = indptr[d + 1];
  float4 s = make_float4(0.f, 0.f, 0.f, 0.f);
  for (int j = lo; j < hi; j++) {
    float4 v = ((const float4*)(src + (size_t)idx[j] * D))[k4];
    s.x += v.x; s.y += v.y; s.z += v.z; s.w += v.w;
  }
  int c = hi - lo;
  float inv = 1.f / (float)(c > 0 ? c : 1);
  s.x *= inv; s.y *= inv; s.z *= inv; s.w *= inv;
  ushort4 h, l;
  h.x = f2bf(s.x); l.x = f2bf(s.x - bf2f(h.x));
  h.y = f2bf(s.y); l.y = f2bf(s.y - bf2f(h.y));
  h.z = f2bf(s.z); l.z = f2bf(s.z - bf2f(h.z));
  h.w = f2bf(s.w); l.w = f2bf(s.w - bf2f(h.w));
  ((ushort4*)(dh + (size_t)d * D))[k4] = h;
  ((ushort4*)(dl + (size_t)d * D))[k4] = l;
}

// ---------------- plain split for weights ----------------
__global__ void split_kernel(const float* __restrict__ src, unsigned short* __restrict__ dh,
                             unsigned short* __restrict__ dl, int n4) {
  int i = blockIdx.x * 256 + threadIdx.x;
  int stride = gridDim.x * 256;
  for (; i < n4; i += stride) {
    float4 v = ((const float4*)src)[i];
    ushort4 h, l;
    h.x = f2bf(v.x); l.x = f2bf(v.x - bf2f(h.x));
    h.y = f2bf(v.y); l.y = f2bf(v.y - bf2f(h.y));
    h.z = f2bf(v.z); l.z = f2bf(v.z - bf2f(h.z));
    h.w = f2bf(v.w); l.w = f2bf(v.w - bf2f(h.w));
    ((ushort4*)dh)[i] = h;
    ((ushort4*)dl)[i] = l;
  }
}

// ---------------- virtual-K pipelined bf16 NT GEMM ----------------
// C_partial[sk][4096][1024] = sum over virtual K-tiles of A_seg[m][k]*B_seg[n][k].
// 6 segments of length KA each (2 products x 3 split-bf16 sweeps).
// 256x256 tile, BK=32, 8 waves (512 thr), wave tile 128x64 (8x4 frags).
// 4-buffer LDS ring (128KB), 3-tile prefetch depth, 1 barrier + vmcnt(8)/tile.
// Slot swizzle: physical 16B-slot p of row r holds logical slot p^((r>>1)&3).
// Bank proof: a 16-lane column read hits group (4(r&1) + (s^((r>>1)&3)))&7 —
// all 8 values twice over r=0..15 -> 2-way, free (m136). Frag strides (16 rows)
// are ≡0 mod 4 after >>1, so the read XOR is frag-invariant.
#define GLDS(g, l)                                                             \
  __builtin_amdgcn_global_load_lds(                                            \
      (const __attribute__((address_space(1))) void*)(g),                      \
      (__attribute__((address_space(3))) void*)(l), 16, 0, 0)

#define SEGA(si) ((si)==0?A0s:(si)==1?A1s:(si)==2?A2s:(si)==3?A3s:(si)==4?A4s:A5s)
#define SEGB(si) ((si)==0?B0s:(si)==1?B1s:(si)==2?B2s:(si)==3?B3s:(si)==4?B4s:B5s)

#define STAGE_A(vt, buf)                                                       \
  {                                                                            \
    int si_ = (vt) >> segshift;                                                \
    size_t ko_ = (size_t)((vt) & segmask) * TBK;                               \
    const unsigned short* As_ = SEGA(si_);                                     \
    GLDS(As_ + gA0 + ko_, &sm[buf][0][uA0 * 8]);                               \
    GLDS(As_ + gA1 + ko_, &sm[buf][0][uA1 * 8]);                               \
  }
#define STAGE_B(vt, buf)                                                       \
  {                                                                            \
    int si_ = (vt) >> segshift;                                                \
    size_t ko_ = (size_t)((vt) & segmask) * TBK;                               \
    const unsigned short* Bs_ = SEGB(si_);                                     \
    GLDS(Bs_ + gB0 + ko_, &sm[buf][1][uA0 * 8]);                               \
    GLDS(Bs_ + gB1 + ko_, &sm[buf][1][uA1 * 8]);                               \
  }

__global__ __launch_bounds__(512, 2) void vk_gemm_kernel(
    const unsigned short* __restrict__ A0s, const unsigned short* __restrict__ A1s,
    const unsigned short* __restrict__ A2s, const unsigned short* __restrict__ A3s,
    const unsigned short* __restrict__ A4s, const unsigned short* __restrict__ A5s,
    const unsigned short* __restrict__ B0s, const unsigned short* __restrict__ B1s,
    const unsigned short* __restrict__ B2s, const unsigned short* __restrict__ B3s,
    const unsigned short* __restrict__ B4s, const unsigned short* __restrict__ B5s,
    float* __restrict__ P0, float* __restrict__ P1,
    float* __restrict__ P2, float* __restrict__ P3,
    int KA, int segshift, int tpb) {
  __shared__ unsigned short sm[4][2][8192]; // 4 bufs x {A,B} x 256rows*32k = 128KB
  const int tid = threadIdx.x;
  const int lane = tid & 63;
  const int wid = tid >> 6;            // 8 waves
  const int wm = wid >> 2, wn = wid & 3; // wave tile: rows wm*128.., cols wn*64..

  const int bid = blockIdx.x;                 // 256 blocks
  const int swz = (bid & 7) * 32 + (bid >> 3); // XCD-chunked
  const int sk = swz >> 6;                    // splitK 0..3
  const int tile = swz & 63;                  // 16 m-tiles x 4 n-tiles
  const int bm0 = (tile >> 2) * 256;
  const int bn0 = (tile & 3) * 256;
  const int vt0 = sk * tpb;
  const int segmask = (1 << segshift) - 1;

  // staging: per operand 1024 units of 16B; thread handles units tid, tid+512.
  // physical slot p = u&3 sources logical slot p ^ ((r>>1)&3).
  const int uA0 = tid, uA1 = tid + 512;
  const int r0 = uA0 >> 2, r1 = uA1 >> 2;
  const int q0 = (uA0 & 3) ^ ((r0 >> 1) & 3), q1 = (uA1 & 3) ^ ((r1 >> 1) & 3);
  const size_t gA0 = (size_t)(bm0 + r0) * KA + q0 * 8;
  const size_t gA1 = (size_t)(bm0 + r1) * KA + q1 * 8;
  const size_t gB0 = (size_t)(bn0 + r0) * KA + q0 * 8;
  const size_t gB1 = (size_t)(bn0 + r1) * KA + q1 * 8;

  // ds_read: logical k-slot s=lane>>4 at row r -> physical slot s^((r>>1)&3);
  // frag-row steps are 0 mod 4 after >>1 -> constant per thread.
  const int xslot = ((lane >> 4) ^ (((lane & 15) >> 1) & 3)) * 8;
  const int offA = (wm * 128 + (lane & 15)) * 32 + xslot; // +i*512 per frag
  const int offB = (wn * 64 + (lane & 15)) * 32 + xslot;  // +j*512 per frag

  f32x4 acc[8][4];
#pragma unroll
  for (int i = 0; i < 8; i++)
#pragma unroll
    for (int j = 0; j < 4; j++) acc[i][j] = (f32x4)(0.f);

  // prologue: stage tiles vt0..vt0+2 into bufs 0..2 (tpb >= 48 always)
  STAGE_A(vt0 + 0, 0); STAGE_B(vt0 + 0, 0);
  STAGE_A(vt0 + 1, 1); STAGE_B(vt0 + 1, 1);
  STAGE_A(vt0 + 2, 2); STAGE_B(vt0 + 2, 2);
  asm volatile("s_waitcnt vmcnt(8)" ::: "memory"); // tile 0 landed (own loads)
  asm volatile("" ::: "memory");
  __builtin_amdgcn_s_barrier();                    // everyone's tile-0 loads landed
  asm volatile("" ::: "memory");

#pragma unroll 1
  for (int t = 0; t < tpb; ++t) {
    const int buf = t & 3;
    const unsigned short* smA = &sm[buf][0][0];
    const unsigned short* smB = &sm[buf][1][0];
    short8 av[4], bv[4], aw[4];
    // phase 0: frags i=0..3
#pragma unroll
    for (int i = 0; i < 4; i++) av[i] = *(const short8*)(smA + offA + i * 512);
#pragma unroll
    for (int j = 0; j < 4; j++) bv[j] = *(const short8*)(smB + offB + j * 512);
    if (t + 3 < tpb) STAGE_A(vt0 + t + 3, (t + 3) & 3);
    __builtin_amdgcn_s_setprio(1);
#pragma unroll
    for (int i = 0; i < 4; i++)
#pragma unroll
      for (int j = 0; j < 4; j++)
        acc[i][j] = __builtin_amdgcn_mfma_f32_16x16x32_bf16(av[i], bv[j], acc[i][j], 0, 0, 0);
    __builtin_amdgcn_s_setprio(0);
    // phase 1: frags i=4..7
#pragma unroll
    for (int i = 0; i < 4; i++) aw[i] = *(const short8*)(smA + offA + (i + 4) * 512);
    if (t + 3 < tpb) STAGE_B(vt0 + t + 3, (t + 3) & 3);
    __builtin_amdgcn_s_setprio(1);
#pragma unroll
    for (int i = 0; i < 4; i++)
#pragma unroll
      for (int j = 0; j < 4; j++)
        acc[i + 4][j] = __builtin_amdgcn_mfma_f32_16x16x32_bf16(aw[i], bv[j], acc[i + 4][j], 0, 0, 0);
    __builtin_amdgcn_s_setprio(0);
    // tile boundary: ensure tile t+1 landed, all waves past reads of buf
    if (t + 1 < tpb) {
      if (t + 3 < tpb) {
        asm volatile("s_waitcnt vmcnt(8)" ::: "memory");
      } else if (t + 2 < tpb) {
        asm volatile("s_waitcnt vmcnt(4)" ::: "memory");
      } else {
        asm volatile("s_waitcnt vmcnt(0)" ::: "memory");
      }
      asm volatile("" ::: "memory");
      __builtin_amdgcn_s_barrier();
      asm volatile("" ::: "memory");
    }
  }

  float* P = sk == 0 ? P0 : sk == 1 ? P1 : sk == 2 ? P2 : P3;
  const int rq = (lane >> 4) * 4;
  const int cq = lane & 15;
#pragma unroll
  for (int i = 0; i < 8; i++) {
#pragma unroll
    for (int j = 0; j < 4; j++) {
#pragma unroll
      for (int e = 0; e < 4; e++) {
        int row = bm0 + wm * 128 + i * 16 + rq + e;
        int col = bn0 + wn * 64 + j * 16 + cq;
        P[(size_t)row * 1024 + col] = acc[i][j][e];
      }
    }
  }
}

// ---------------- combine4: C = leaky(P0..P3 + bias[row]) + hi/lo split --------
__global__ void combine_split_kernel(const float* __restrict__ P0, const float* __restrict__ P1,
                                     const float* __restrict__ P2, const float* __restrict__ P3,
                                     const float* __restrict__ bias, float* __restrict__ Cf,
                                     unsigned short* __restrict__ Ch,
                                     unsigned short* __restrict__ Cl) {
  int i = blockIdx.x * 256 + threadIdx.x; // float4 index, 1M total
  float4 a = ((const float4*)P0)[i];
  float4 b = ((const float4*)P1)[i];
  float4 c = ((const float4*)P2)[i];
  float4 d = ((const float4*)P3)[i];
  float bb = bias[(i * 4) >> 10];
  float4 v;
  v.x = a.x + b.x + c.x + d.x + bb;
  v.y = a.y + b.y + c.y + d.y + bb;
  v.z = a.z + b.z + c.z + d.z + bb;
  v.w = a.w + b.w + c.w + d.w + bb;
  v.x = v.x > 0.f ? v.x : 0.01f * v.x;
  v.y = v.y > 0.f ? v.y : 0.01f * v.y;
  v.z = v.z > 0.f ? v.z : 0.01f * v.z;
  v.w = v.w > 0.f ? v.w : 0.01f * v.w;
  ((float4*)Cf)[i] = v;
  ushort4 h, l;
  h.x = f2bf(v.x); l.x = f2bf(v.x - bf2f(h.x));
  h.y = f2bf(v.y); l.y = f2bf(v.y - bf2f(h.y));
  h.z = f2bf(v.z); l.z = f2bf(v.z - bf2f(h.z));
  h.w = f2bf(v.w); l.w = f2bf(v.w - bf2f(h.w));
  ((ushort4*)Ch)[i] = h;
  ((ushort4*)Cl)[i] = l;
}

// ---------------- combine4: C = leaky(P0..P3 + bias[col]) ----------------
__global__ void combine_kernel(const float* __restrict__ P0, const float* __restrict__ P1,
                               const float* __restrict__ P2, const float* __restrict__ P3,
                               const float* __restrict__ bias, float* __restrict__ C) {
  int i = blockIdx.x * 256 + threadIdx.x;
  float4 a = ((const float4*)P0)[i];
  float4 b = ((const float4*)P1)[i];
  float4 c = ((const float4*)P2)[i];
  float4 d = ((const float4*)P3)[i];
  float4 bb = *(const float4*)(bias + ((i * 4) & 1023));
  float4 v;
  v.x = a.x + b.x + c.x + d.x + bb.x;
  v.y = a.y + b.y + c.y + d.y + bb.y;
  v.z = a.z + b.z + c.z + d.z + bb.z;
  v.w = a.w + b.w + c.w + d.w + bb.w;
  v.x = v.x > 0.f ? v.x : 0.01f * v.x;
  v.y = v.y > 0.f ? v.y : 0.01f * v.y;
  v.z = v.z > 0.f ? v.z : 0.01f * v.z;
  v.w = v.w > 0.f ? v.w : 0.01f * v.w;
  ((float4*)C)[i] = v;
}

extern "C" void kernel_launch(void* const* d_in, const int* in_sizes, int n_in,
                              void* d_out, int out_size, void* d_ws, size_t ws_size,
                              hipStream_t stream) {
  const float* x      = (const float*)d_in[0];
  const float* col_Wl = (const float*)d_in[1];
  const float* col_Wr = (const float*)d_in[2];
  const float* col_b  = (const float*)d_in[3];
  const float* row_Wl = (const float*)d_in[4];
  const float* row_Wr = (const float*)d_in[5];
  const float* row_b  = (const float*)d_in[6];
  const int*   knn    = (const int*)d_in[7];   // [2][KNN_E]
  const int*   genet  = (const int*)d_in[8];   // [2][GENET_E]
  float* out = (float*)d_out;

  const size_t MAT = (size_t)COL_DIM * ROW_DIM; // 4M elements
  const size_t WCOL = (size_t)COL_DIM * COL_DIM; // 16M
  const size_t WROW = (size_t)ROW_DIM * ROW_DIM; // 1M
  char* w = (char*)d_ws;
  float* X1f = (float*)w; w += MAT * 4;                 // ET then E1 (fp32)
  unsigned short* X2h = (unsigned short*)w; w += MAT * 2; // ETh/l then E1h/l
  unsigned short* X2l = (unsigned short*)w; w += MAT * 2;
  unsigned short* X3h = (unsigned short*)w; w += MAT * 2; // Mh/l then Gh/l
  unsigned short* X3l = (unsigned short*)w; w += MAT * 2;
  unsigned short* WLh = (unsigned short*)w; w += WCOL * 2; // 32MB
  unsigned short* WLl = (unsigned short*)w; w += WCOL * 2;
  unsigned short* WRh = (unsigned short*)w; w += WCOL * 2;
  unsigned short* WRl = (unsigned short*)w; w += WCOL * 2;
  unsigned short* RLh = (unsigned short*)w; w += WROW * 2; // 2MB
  unsigned short* RLl = (unsigned short*)w; w += WROW * 2;
  unsigned short* RRh = (unsigned short*)w; w += WROW * 2;
  unsigned short* RRl = (unsigned short*)w; w += WROW * 2;
  float* PP0 = (float*)w; w += MAT * 4;
  float* PP1 = (float*)w; w += MAT * 4;
  float* PP2 = (float*)w; w += MAT * 4;
  float* PP3 = (float*)w; w += MAT * 4;
  int* kcnt = (int*)w; w += 1024 * 4;
  int* kptr = (int*)w; w += 1025 * 4;
  int* kidx = (int*)w; w += KNN_E * 4;
  int* gcnt = (int*)w; w += 4096 * 4;
  int* gptr = (int*)w; w += 4097 * 4;
  int* gidx = (int*)w; w += (size_t)GENET_E * 4;

  // ---- CSR build (deterministic via per-bucket value sort) ----
  hipMemsetAsync(kcnt, 0, 1024 * 4, stream);
  hipMemsetAsync(gcnt, 0, 4096 * 4, stream);
  count_kernel<<<KNN_E / 256, 256, 0, stream>>>(knn + KNN_E, KNN_E, kcnt);
  count_kernel<<<GENET_E / 256, 256, 0, stream>>>(genet + GENET_E, GENET_E, gcnt);
  scan_kernel<<<1, 1024, 0, stream>>>(kcnt, kptr, 1024);
  scan_kernel<<<1, 1024, 0, stream>>>(gcnt, gptr, 4096);
  copy_int_kernel<<<4, 256, 0, stream>>>(kptr, kcnt, 1024);
  copy_int_kernel<<<16, 256, 0, stream>>>(gptr, gcnt, 4096);
  fill_kernel<<<KNN_E / 256, 256, 0, stream>>>(knn, knn + KNN_E, KNN_E, kcnt, kidx);
  fill_kernel<<<GENET_E / 256, 256, 0, stream>>>(genet, genet + GENET_E, GENET_E, gcnt, gidx);
  rank_sort_kernel<<<256, 256, 0, stream>>>(kptr, kidx, 1024);
  rank_sort_kernel<<<1024, 256, 0, stream>>>(gptr, gidx, 4096);

  const float* Ein = x;
  for (int i = 0; i < NUM_LAYERS; i++) {
    const float* cWl = col_Wl + (size_t)i * WCOL;
    const float* cWr = col_Wr + (size_t)i * WCOL;
    const float* cb  = col_b + (size_t)i * COL_DIM;
    const float* rWl = row_Wl + (size_t)i * WROW;
    const float* rWr = row_Wr + (size_t)i * WROW;
    const float* rb  = row_b + (size_t)i * ROW_DIM;

    // ---- column branch: E1 = leaky(cWl@M^T + cWr@ET^T + cb[row]) ----
    transpose_split_kernel<<<dim3(ROW_DIM / 32, COL_DIM / 32), dim3(32, 8), 0, stream>>>(
        Ein, X1f, X2h, X2l, COL_DIM, ROW_DIM);
    agg_slice_kernel<<<dim3(8, 512), 256, 0, stream>>>(X1f, X3h, X3l, kptr, kidx,
                                                       COL_DIM, 7);
    split_kernel<<<2048, 256, 0, stream>>>(cWl, WLh, WLl, (int)(WCOL / 4));
    split_kernel<<<2048, 256, 0, stream>>>(cWr, WRh, WRl, (int)(WCOL / 4));
    // segments: (WLh,Mh)(WLh,Ml)(WLl,Mh) (WRh,ETh)(WRh,ETl)(WRl,ETh)
    vk_gemm_kernel<<<256, 512, 0, stream>>>(
        WLh, WLh, WLl, WRh, WRh, WRl,
        X3h, X3l, X3h, X2h, X2l, X2h,
        PP0, PP1, PP2, PP3, COL_DIM, 7, 192);
    combine_split_kernel<<<4096, 256, 0, stream>>>(PP0, PP1, PP2, PP3, cb,
                                                   X1f, X2h, X2l); // E1 f32+h/l
    // ---- row branch: out = leaky(G@rWl^T + E1@rWr^T + rb[col]) ----
    agg_slice_kernel<<<dim3(8, 512), 256, 0, stream>>>(X1f, X3h, X3l, gptr, gidx,
                                                       ROW_DIM, 5);
    split_kernel<<<1024, 256, 0, stream>>>(rWl, RLh, RLl, (int)(WROW / 4));
    split_kernel<<<1024, 256, 0, stream>>>(rWr, RRh, RRl, (int)(WROW / 4));
    // segments: (Gh,RLh)(Gh,RLl)(Gl,RLh) (E1h,RRh)(E1h,RRl)(E1l,RRh)
    vk_gemm_kernel<<<256, 512, 0, stream>>>(
        X3h, X3h, X3l, X2h, X2h, X2l,
        RLh, RLl, RLh, RRh, RRl, RRh,
        PP0, PP1, PP2, PP3, ROW_DIM, 5, 48);
    combine_kernel<<<4096, 256, 0, stream>>>(PP0, PP1, PP2, PP3, rb, out);

    Ein = out;
  }
}